// Round 2
// baseline (595.901 us; speedup 1.0000x reference)
//
#include <hip/hip_runtime.h>

// out[b, j, k] for k in [0,20): i=k/2, c=k%2, m = j*B + b - i
//   = (m >= 0) ? inputs[m/30, 0, c] * w_c[m%30] : 0
// out[b, j, k] for k in [20,28) = inputs[b, j, k-18]
// Row-major: inputs (B,30,10), out (B,30,28). row = b*30 + j.

__global__ __launch_bounds__(256) void assign_kernel(
    const float* __restrict__ inp,
    const float* __restrict__ w1,
    const float* __restrict__ w2,
    float* __restrict__ out,
    int B, int nrows) {
    __shared__ float w1s[32], w2s[32];
    int t = threadIdx.x;
    if (t < 30) w1s[t] = w1[t];
    else if (t >= 32 && t < 62) w2s[t - 32] = w2[t - 32];
    __syncthreads();

    int row = blockIdx.x * blockDim.x + t;
    if (row >= nrows) return;

    int b = row / 30;           // magic-mul division
    int j = row - b * 30;
    int m0 = j * B + b;         // < 2^22, fits easily
    int q0 = m0 / 30;
    int r0 = m0 - q0 * 30;

    // The 10 taps m = m0-i (i=0..9) only touch source rows q0 and q0-1.
    float2 xa = *(const float2*)(inp + (size_t)q0 * 300);
    float2 xb = (q0 >= 1) ? *(const float2*)(inp + (size_t)(q0 - 1) * 300)
                          : make_float2(0.f, 0.f);

    float front[20];
#pragma unroll
    for (int i = 0; i < 10; ++i) {
        bool useA = (r0 >= i);
        float2 x = useA ? xa : xb;
        int r = useA ? (r0 - i) : (r0 - i + 30);
        bool valid = useA || (q0 >= 1);   // invalid only when q0==0 && i>r0 (m<0)
        front[2 * i]     = valid ? x.x * w1s[r] : 0.f;
        front[2 * i + 1] = valid ? x.y * w2s[r] : 0.f;
    }

    // Tail: inputs[b, j, 2..9] = 8 floats at row*10+2 (8B-aligned).
    const float* tin = inp + (size_t)row * 10 + 2;
    float2 t0 = *(const float2*)(tin + 0);
    float2 t1 = *(const float2*)(tin + 2);
    float2 t2 = *(const float2*)(tin + 4);
    float2 t3 = *(const float2*)(tin + 6);

    float4* o4 = (float4*)(out + (size_t)row * 28);   // rows are 112B, 16B-aligned
    o4[0] = make_float4(front[0],  front[1],  front[2],  front[3]);
    o4[1] = make_float4(front[4],  front[5],  front[6],  front[7]);
    o4[2] = make_float4(front[8],  front[9],  front[10], front[11]);
    o4[3] = make_float4(front[12], front[13], front[14], front[15]);
    o4[4] = make_float4(front[16], front[17], front[18], front[19]);
    o4[5] = make_float4(t0.x, t0.y, t1.x, t1.y);
    o4[6] = make_float4(t2.x, t2.y, t3.x, t3.y);
}

extern "C" void kernel_launch(void* const* d_in, const int* in_sizes, int n_in,
                              void* d_out, int out_size, void* d_ws, size_t ws_size,
                              hipStream_t stream) {
    const float* inp = (const float*)d_in[0];
    const float* w1  = (const float*)d_in[1];
    const float* w2  = (const float*)d_in[2];
    float* out = (float*)d_out;

    int B = in_sizes[0] / 300;      // inputs is (B, 30, 10)
    int nrows = B * 30;
    int block = 256;
    int grid = (nrows + block - 1) / block;
    assign_kernel<<<grid, block, 0, stream>>>(inp, w1, w2, out, B, nrows);
}

// Round 5
// 557.189 us; speedup vs baseline: 1.0695x; 1.0695x over previous
//
#include <hip/hip_runtime.h>

// out[b, j, k] for k in [0,20): i=k/2, c=k%2, m = j*B + b - i
//   = (m >= 0) ? inputs[m/30, 0, c] * w_c[m%30] : 0
// out[b, j, k] for k in [20,28) = inputs[b, j, k-18]
// Row-major: inputs (B,30,10), out (B,30,28). row = b*30 + j.
//
// Structure (round 3):
//  - pack_kernel compacts inputs[:,0,0:2] -> 1MB float2 buffer in d_ws so the
//    main kernel's scattered gather is L2-resident (4MB/XCD) instead of
//    spraying 8B reads over the 157MB input.
//  - main kernel: 192 rows/block. Input rows staged to LDS via contiguous
//    float4 reads; output staged in LDS [192][29] (stride 29 coprime with 32
//    banks -> conflict-free) then written as lane-contiguous float4s.

__global__ __launch_bounds__(256) void pack_kernel(const float* __restrict__ inp,
                                                   float2* __restrict__ xc, int B) {
    int q = blockIdx.x * blockDim.x + threadIdx.x;
    if (q < B) {
        const float* p = inp + (size_t)q * 300;
        xc[q] = make_float2(p[0], p[1]);
    }
}

#define ROWS 192   // rows per block (= threads per block), 3 waves

__global__ __launch_bounds__(ROWS) void main_kernel(
    const float* __restrict__ inp,
    const float2* __restrict__ xc,
    const float* __restrict__ w1,
    const float* __restrict__ w2,
    float* __restrict__ out,
    int B, int nrows) {
    __shared__ float w1s[30], w2s[30];
    __shared__ float lin[ROWS * 10];        // staged input rows
    __shared__ float lout[ROWS * 29];       // staged output rows, padded 28->29

    int t = threadIdx.x;
    int base = blockIdx.x * ROWS;

    if (t < 30) w1s[t] = w1[t];
    else if (t >= 32 && t < 62) w2s[t - 32] = w2[t - 32];

    // Cooperative contiguous read: ROWS*10 floats = ROWS*10/4 float4s.
    {
        const float4* gin = (const float4*)(inp + (size_t)base * 10);  // 16B-aligned
        float4* l4 = (float4*)lin;
        const int nf4 = ROWS * 10 / 4;                 // 480
        const int gcap = nrows * 10 / 4;
#pragma unroll
        for (int s = 0; s < (nf4 + ROWS - 1) / ROWS; ++s) {
            int idx = t + ROWS * s;
            if (idx < nf4 && base * 10 / 4 + idx < gcap) l4[idx] = gin[idx];
        }
    }
    __syncthreads();

    // Compute this thread's row into lout.
    {
        int row = base + t;
        if (row >= nrows) row = nrows - 1;   // clamp; global write is guarded
        int b = row / 30;
        int j = row - b * 30;
        int m0 = j * B + b;
        int q0 = m0 / 30;
        int r0 = m0 - q0 * 30;

        float2 xa = xc[q0];                                   // L2-hot 1MB buffer
        float2 xb = (q0 >= 1) ? xc[q0 - 1] : make_float2(0.f, 0.f);

        float* lo = lout + t * 29;
#pragma unroll
        for (int i = 0; i < 10; ++i) {
            bool useA = (r0 >= i);
            float2 x = useA ? xa : xb;
            int r = useA ? (r0 - i) : (r0 - i + 30);
            bool valid = useA || (q0 >= 1);
            lo[2 * i]     = valid ? x.x * w1s[r] : 0.f;
            lo[2 * i + 1] = valid ? x.y * w2s[r] : 0.f;
        }
#pragma unroll
        for (int u = 0; u < 8; ++u) lo[20 + u] = lin[t * 10 + 2 + u];
    }
    __syncthreads();

    // Coalesced write: ROWS*28 floats = ROWS*7 float4s, 7 per thread,
    // lane-contiguous per instruction.
    {
        float4* gout = (float4*)(out + (size_t)base * 28);
        const long long gcap = (long long)nrows * 7;
#pragma unroll
        for (int s = 0; s < 7; ++s) {
            int g = t + ROWS * s;
            int r = g / 7;
            int c4 = g - r * 7;
            const float* lp = lout + r * 29 + c4 * 4;
            if ((long long)base * 7 + g < gcap)
                gout[g] = make_float4(lp[0], lp[1], lp[2], lp[3]);
        }
    }
}

extern "C" void kernel_launch(void* const* d_in, const int* in_sizes, int n_in,
                              void* d_out, int out_size, void* d_ws, size_t ws_size,
                              hipStream_t stream) {
    const float* inp = (const float*)d_in[0];
    const float* w1  = (const float*)d_in[1];
    const float* w2  = (const float*)d_in[2];
    float* out = (float*)d_out;

    int B = in_sizes[0] / 300;      // inputs is (B, 30, 10)
    int nrows = B * 30;

    float2* xc = (float2*)d_ws;     // B float2s = 1MB

    pack_kernel<<<(B + 255) / 256, 256, 0, stream>>>(inp, xc, B);

    int grid = (nrows + ROWS - 1) / ROWS;   // 20480 for B=131072 (exact)
    main_kernel<<<grid, ROWS, 0, stream>>>(inp, xc, w1, w2, out, B, nrows);
}

// Round 12
// 544.654 us; speedup vs baseline: 1.0941x; 1.0230x over previous
//
#include <hip/hip_runtime.h>

// out[b, j, k] for k in [0,20): i=k/2, c=k%2, m = j*B + b - i
//   = (m >= 0) ? inputs[m/30, 0, c] * w_c[m%30] : 0
// out[b, j, k] for k in [20,28) = inputs[b, j, k-18]
// Row-major: inputs (B,30,10), out (B,30,28). row = b*30 + j.
//
// Round 7 = round 6 with the nontemporal-store type fixed (native clang
// vector type instead of HIP_vector_type float4):
//  - pack_kernel: inputs[:,0,0:2] -> 1MB float2 xc buffer (L2-resident).
//  - main_kernel, 256 rows/block:
//      * block needs only xc[q] for q in {qbase_j-1, qbase_j, qbase_j+1},
//        j=0..29 (b-b0 < 10 < 30 ==> q0 - qbase_j in {0,1}); 90 cooperative
//        scattered loads/block replace 512 per-lane scattered loads.
//      * tail (cols 2..9) read directly from global (full line utilization
//        across the wave), issued early to hide latency under table build.
//      * output staged in LDS [256][29] (stride 29 coprime 32 -> conflict
//        free), then written as lane-contiguous nontemporal float4s so the
//        440MB stream doesn't evict xc from L2.

typedef float f32x4 __attribute__((ext_vector_type(4)));

__global__ __launch_bounds__(256) void pack_kernel(const float* __restrict__ inp,
                                                   float2* __restrict__ xc, int B) {
    int q = blockIdx.x * blockDim.x + threadIdx.x;
    if (q < B) {
        const float* p = inp + (size_t)q * 300;
        xc[q] = make_float2(p[0], p[1]);
    }
}

#define ROWS 256

__global__ __launch_bounds__(ROWS) void main_kernel(
    const float* __restrict__ inp,
    const float2* __restrict__ xc,
    const float* __restrict__ w1,
    const float* __restrict__ w2,
    float* __restrict__ out,
    int B, int nrows) {
    __shared__ float w1s[30], w2s[30];
    __shared__ float2 xq[30][3];    // xc[qbase_j + {-1,0,1}]
    __shared__ int qb[30];          // qbase_j
    __shared__ float lout[ROWS * 29];

    int t = threadIdx.x;
    int base = blockIdx.x * ROWS;
    int b0 = base / 30;

    int row = base + t;
    int rowc = (row < nrows) ? row : (nrows - 1);

    // Tail loads issued early (independent of the xq table).
    const float2* tin = (const float2*)(inp + (size_t)rowc * 10 + 2);
    float2 t0 = tin[0];
    float2 t1 = tin[1];
    float2 t2 = tin[2];
    float2 t3 = tin[3];

    // Cooperative gather table: 90 scattered 8B loads for the whole block.
    if (t < 90) {
        int jj = t / 3;
        int dq = t - jj * 3;                  // 0,1,2
        int qbase = (jj * B + b0) / 30;
        int q = qbase + dq - 1;
        float2 v = (q >= 0 && q < B) ? xc[q] : make_float2(0.f, 0.f);
        xq[jj][dq] = v;
        if (dq == 1) qb[jj] = qbase;
    } else if (t >= 96 && t < 126) {
        w1s[t - 96] = w1[t - 96];
    } else if (t >= 128 && t < 158) {
        w2s[t - 128] = w2[t - 128];
    }
    __syncthreads();

    // Compute this thread's row into lout.
    {
        int b = rowc / 30;
        int j = rowc - b * 30;
        int m0 = j * B + b;
        int q0 = m0 / 30;
        int r0 = m0 - q0 * 30;

        int ia = q0 - qb[j] + 1;              // 1 or 2 (proved in header)
        float2 xa = xq[j][ia];                // LDS broadcast within j-group
        float2 xb = xq[j][ia - 1];

        float* lo = lout + t * 29;
#pragma unroll
        for (int i = 0; i < 10; ++i) {
            bool useA = (r0 >= i);
            float2 x = useA ? xa : xb;
            int r = useA ? (r0 - i) : (r0 - i + 30);
            bool valid = (m0 - i) >= 0;
            lo[2 * i]     = valid ? x.x * w1s[r] : 0.f;
            lo[2 * i + 1] = valid ? x.y * w2s[r] : 0.f;
        }
        lo[20] = t0.x; lo[21] = t0.y; lo[22] = t1.x; lo[23] = t1.y;
        lo[24] = t2.x; lo[25] = t2.y; lo[26] = t3.x; lo[27] = t3.y;
    }
    __syncthreads();

    // Coalesced nontemporal write: ROWS*7 float4s, lane-contiguous.
    {
        f32x4* gout = (f32x4*)(out + (size_t)base * 28);
        const long long gcap = (long long)nrows * 7;
#pragma unroll
        for (int s = 0; s < 7; ++s) {
            int g = t + ROWS * s;
            int r = g / 7;
            int c4 = g - r * 7;
            const float* lp = lout + r * 29 + c4 * 4;
            if ((long long)base * 7 + g < gcap) {
                f32x4 v = {lp[0], lp[1], lp[2], lp[3]};
                __builtin_nontemporal_store(v, &gout[g]);
            }
        }
    }
}

extern "C" void kernel_launch(void* const* d_in, const int* in_sizes, int n_in,
                              void* d_out, int out_size, void* d_ws, size_t ws_size,
                              hipStream_t stream) {
    const float* inp = (const float*)d_in[0];
    const float* w1  = (const float*)d_in[1];
    const float* w2  = (const float*)d_in[2];
    float* out = (float*)d_out;

    int B = in_sizes[0] / 300;      // inputs is (B, 30, 10)
    int nrows = B * 30;

    float2* xc = (float2*)d_ws;     // B float2s = 1MB

    pack_kernel<<<(B + 255) / 256, 256, 0, stream>>>(inp, xc, B);

    int grid = (nrows + ROWS - 1) / ROWS;   // 15360 for B=131072 (exact)
    main_kernel<<<grid, ROWS, 0, stream>>>(inp, xc, w1, w2, out, B, nrows);
}